// Round 1
// baseline (68.289 us; speedup 1.0000x reference)
//
#include <hip/hip_runtime.h>

#define S_LEN 8192
#define DIM   256
#define NHP   16      // heads padded to 16
#define CHUNK 512
#define TB    64
#define NIT   8

typedef __attribute__((ext_vector_type(8))) short          short8;
typedef __attribute__((ext_vector_type(4))) unsigned short u16x4;
typedef __attribute__((ext_vector_type(4))) float          f32x4;
typedef __attribute__((ext_vector_type(8))) __bf16         bf16x8;

static __device__ __forceinline__ unsigned short f2bf(float f){
  unsigned int u = __builtin_bit_cast(unsigned int, f);
  u = (u + 0x7fffu + ((u >> 16) & 1u)) >> 16;   // RNE
  return (unsigned short)u;
}
static __device__ __forceinline__ float bf2f(unsigned short h){
  unsigned int u = ((unsigned int)h) << 16;
  return __builtin_bit_cast(float, u);
}
static __device__ __forceinline__ float fast_tanh(float x){
  float e = __expf(2.0f * x);          // saturates correctly for |x| large
  return 1.0f - 2.0f / (e + 1.0f);
}
static __device__ __forceinline__ f32x4 mfma_bf16(short8 a, short8 b, f32x4 c){
  return __builtin_amdgcn_mfma_f32_16x16x32_bf16(
      __builtin_bit_cast(bf16x8, a), __builtin_bit_cast(bf16x8, b), c, 0, 0, 0);
}

// ---- prep: KT[n][k] = bf16(k_kernel[k][n])  (A-operand of h^T = K^T X^T)
__global__ void k_prep(const float* __restrict__ kk, unsigned short* __restrict__ KT){
  int idx = blockIdx.x * 512 + threadIdx.x;     // 128 x 512 = 65536
  int n = idx >> 8, k = idx & 255;
  KT[(n << 8) + k] = f2bf(kk[(k << 8) + n]);
}

// ---- main fused kernel: one block = one (batch, 512-row chunk)
__global__ __launch_bounds__(512, 2) void k_main(
    const float* __restrict__ x, const int* __restrict__ mask,
    const float* __restrict__ ok, const unsigned short* __restrict__ KT,
    float* __restrict__ ACC, float* __restrict__ ML)
{
  __shared__ __align__(16) unsigned char sXA[32768];   // x tile [64][256] bf16, row-major, swz ((row&7)<<4)
  __shared__ __align__(16) unsigned char sXT[32768];   // x tile [256][64] bf16, d-major,  swz (((d>>2)&7)<<4)
  __shared__ __align__(16) unsigned char sT2[32768];   // tanh(h) [64][256] bf16, row-major, swz ((row&7)<<4)
  __shared__ __align__(16) unsigned char sOT[16*528];  // O^T [16][256] bf16 (+pad), rows 8..15 zero
  __shared__ __align__(16) unsigned char sPT[16*144];  // P^T [16][64] bf16 (+pad)
  __shared__ float sWMax[4][16];
  __shared__ float sWSum[4][16];
  __shared__ float sMrun[16];
  __shared__ float sLrun[16];
  __shared__ float sMaskB[CHUNK];

  const int tid = threadIdx.x;
  const int w   = tid >> 6;      // wave 0..7
  const int l   = tid & 63;
  const int l15 = l & 15;
  const int lhi = l >> 4;        // 0..3
  const int bid = blockIdx.x;
  const int b   = bid >> 4;
  const int chunk0 = (bid & 15) * CHUNK;

  // O^T init (heads 8..15 zero-padded)
  for (int idx = tid; idx < NHP * 256; idx += 512){
    int h = idx >> 8, k = idx & 255;
    float v = (h < 8) ? ok[k * 8 + h] : 0.0f;
    *(unsigned short*)(sOT + h * 528 + k * 2) = f2bf(v);
  }
  if (tid < 16){ sMrun[tid] = -1e30f; sLrun[tid] = 0.0f; }
  sMaskB[tid] = mask[(size_t)b * S_LEN + chunk0 + tid] ? 0.0f : 1e12f;

  // persistent K^T fragments: wave w owns hidden cols [32w, 32w+32)
  short8 aF[2][8];
  #pragma unroll
  for (int mi = 0; mi < 2; ++mi){
    int hidA = l15 + ((2*w + mi) << 4);
    #pragma unroll
    for (int k = 0; k < 8; ++k){
      int col = (k << 5) + (lhi << 3);
      aF[mi][k] = *(const short8*)((const unsigned char*)KT + (((size_t)hidA << 8) + col) * 2);
    }
  }

  // first x tile into regs: per wave-iter i8, wave covers row rl = i8*8+w, lane covers d = 4l..4l+3
  const unsigned char* xb = (const unsigned char*)(x + ((size_t)b * S_LEN + chunk0) * DIM);
  f32x4 xr[8];
  #pragma unroll
  for (int i8 = 0; i8 < 8; ++i8){
    int rl = i8 * 8 + w;
    xr[i8] = *(const f32x4*)(xb + ((size_t)rl * DIM + l * 4) * 4);
  }

  f32x4 acc3[2];
  acc3[0] = (f32x4){0.f,0.f,0.f,0.f};
  acc3[1] = acc3[0];
  float m_new = -1e30f, fsc = 0.0f;

  __syncthreads();

  for (int it = 0; it < NIT; ++it){
    // ---- P0: stage current tile to LDS (XA + XT), then issue next tile's loads
    #pragma unroll
    for (int i8 = 0; i8 < 8; ++i8){
      int rl = i8 * 8 + w;
      u16x4 v;
      v[0]=f2bf(xr[i8][0]); v[1]=f2bf(xr[i8][1]); v[2]=f2bf(xr[i8][2]); v[3]=f2bf(xr[i8][3]);
      *(u16x4*)(sXA + rl * 512 + ((l * 8) ^ ((rl & 7) << 4))) = v;
      #pragma unroll
      for (int i = 0; i < 4; ++i){
        int d = l * 4 + i;          // d>>2 == l
        *(unsigned short*)(sXT + d * 128 + ((rl * 2) ^ ((l & 7) << 4))) = v[i];
      }
    }
    if (it + 1 < NIT){
      #pragma unroll
      for (int i8 = 0; i8 < 8; ++i8){
        int rl = i8 * 8 + w;
        xr[i8] = *(const f32x4*)(xb + (((size_t)(it+1) * TB + rl) * DIM + l * 4) * 4);
      }
    }
    __syncthreads();

    // ---- P1: GEMM1^T: h^T[hid][row] = K^T · X^T ; tanh -> sT2[row][hid]
    #pragma unroll
    for (int nt = 0; nt < 4; ++nt){
      int row = l15 + (nt << 4);
      f32x4 a0 = (f32x4){0.f,0.f,0.f,0.f};
      f32x4 a1 = a0;
      #pragma unroll
      for (int k = 0; k < 8; ++k){
        int col2 = (k << 6) + (lhi << 4);   // byte offset of k-chunk
        short8 bF = *(const short8*)(sXA + row * 512 + (col2 ^ ((row & 7) << 4)));
        a0 = mfma_bf16(aF[0][k], bF, a0);
        a1 = mfma_bf16(aF[1][k], bF, a1);
      }
      #pragma unroll
      for (int mi = 0; mi < 2; ++mi){
        f32x4 av = mi ? a1 : a0;
        u16x4 tv;
        #pragma unroll
        for (int r = 0; r < 4; ++r) tv[r] = f2bf(fast_tanh(av[r]));
        int hidb2 = ((((2*w + mi) << 4) + (lhi << 2))) * 2;
        *(u16x4*)(sT2 + row * 512 + (hidb2 ^ ((row & 7) << 4))) = tv;
      }
    }
    __syncthreads();

    // ---- P2: GEMM2: scores[row][head] = tanh(h) · O   (waves 0..3)
    float sc[4];
    if (w < 4){
      int row = l15 + (w << 4);
      f32x4 a2 = (f32x4){0.f,0.f,0.f,0.f};
      #pragma unroll
      for (int k = 0; k < 8; ++k){
        int col2 = (k << 6) + (lhi << 4);
        short8 aT = *(const short8*)(sT2 + row * 512 + (col2 ^ ((row & 7) << 4)));
        short8 bO = *(const short8*)(sOT + l15 * 528 + col2);
        a2 = mfma_bf16(aT, bO, a2);
      }
      int rbase = (w << 4) + (lhi << 2);
      #pragma unroll
      for (int r = 0; r < 4; ++r)
        sc[r] = a2[r] - sMaskB[it * TB + rbase + r];
      float vm = fmaxf(fmaxf(sc[0], sc[1]), fmaxf(sc[2], sc[3]));
      vm = fmaxf(vm, __shfl_xor(vm, 16));
      vm = fmaxf(vm, __shfl_xor(vm, 32));
      if (l < 16) sWMax[w][l] = vm;
    }
    __syncthreads();

    // ---- P3: online-softmax bookkeeping + P tile
    float m_old = sMrun[l15];
    float wm = fmaxf(fmaxf(sWMax[0][l15], sWMax[1][l15]),
                     fmaxf(sWMax[2][l15], sWMax[3][l15]));
    m_new = fmaxf(m_old, wm);
    fsc = __expf(m_old - m_new);
    acc3[0] *= fsc;
    acc3[1] *= fsc;
    if (w < 4){
      float psum = 0.0f;
      int rbase = (w << 4) + (lhi << 2);
      #pragma unroll
      for (int r = 0; r < 4; ++r){
        float p = __expf(sc[r] - m_new);
        unsigned short pb = f2bf(p);
        psum += bf2f(pb);                 // denominator matches bf16-rounded numerator
        *(unsigned short*)(sPT + l15 * 144 + (rbase + r) * 2) = pb;
      }
      psum += __shfl_xor(psum, 16);
      psum += __shfl_xor(psum, 32);
      if (l < 16) sWSum[w][l] = psum;
    }
    __syncthreads();

    // ---- P4: GEMM3: pooled^T[d][head] += X^T · P
    #pragma unroll
    for (int mi = 0; mi < 2; ++mi){
      int d = l15 + ((2*w + mi) << 4);
      #pragma unroll
      for (int kc = 0; kc < 2; ++kc){
        int r2 = ((kc << 5) + (lhi << 3)) * 2;
        short8 aX = *(const short8*)(sXT + d * 128 + (r2 ^ (((d >> 2) & 7) << 4)));
        short8 bP = *(const short8*)(sPT + l15 * 144 + r2);
        acc3[mi] = mfma_bf16(aX, bP, acc3[mi]);
      }
    }
    if (w == 0 && l < 16){
      sLrun[l] = sLrun[l] * fsc + sWSum[0][l] + sWSum[1][l] + sWSum[2][l] + sWSum[3][l];
      sMrun[l] = m_new;
    }
    __syncthreads();
  }

  // epilogue: per-chunk partials
  #pragma unroll
  for (int mi = 0; mi < 2; ++mi){
    int d0 = ((2*w + mi) << 4) + (lhi << 2);
    *(f32x4*)(ACC + ((size_t)bid * NHP + l15) * 256 + d0) = acc3[mi];
  }
  if (w == 0 && l < 16){
    ML[bid * 32 + l]      = sMrun[l];
    ML[bid * 32 + 16 + l] = sLrun[l];
  }
}

// ---- merge 16 chunk-partials per (batch, head)
__global__ void k_merge(const float* __restrict__ ACC, const float* __restrict__ ML,
                        float* __restrict__ out){
  int b = blockIdx.x >> 3;
  int h = blockIdx.x & 7;
  int d = threadIdx.x;                      // 256
  float M = -1e30f;
  #pragma unroll
  for (int c = 0; c < 16; ++c) M = fmaxf(M, ML[(b * 16 + c) * 32 + h]);
  float L = 0.0f, V = 0.0f;
  #pragma unroll
  for (int c = 0; c < 16; ++c){
    int blk = b * 16 + c;
    float e = __expf(ML[blk * 32 + h] - M);
    L += e * ML[blk * 32 + 16 + h];
    V += e * ACC[((size_t)blk * 16 + h) * 256 + d];
  }
  out[(size_t)b * 2048 + h * 256 + d] = V / L;
}

extern "C" void kernel_launch(void* const* d_in, const int* in_sizes, int n_in,
                              void* d_out, int out_size, void* d_ws, size_t ws_size,
                              hipStream_t stream){
  const float* x   = (const float*)d_in[0];
  const int*  mask = (const int*) d_in[1];
  const float* kk  = (const float*)d_in[2];
  const float* ok  = (const float*)d_in[3];
  float* out = (float*)d_out;

  // ws layout: KT bf16 (128 KiB) | ACC f32 256*16*256 (4 MiB) | ML f32 256*32 (32 KiB)
  unsigned short* KT = (unsigned short*)d_ws;
  float* ACC = (float*)((char*)d_ws + 131072);
  float* ML  = (float*)((char*)d_ws + 131072 + 4194304);

  k_prep <<<128, 512, 0, stream>>>(kk, KT);
  k_main <<<256, 512, 0, stream>>>(x, mask, ok, KT, ACC, ML);
  k_merge<<<128, 256, 0, stream>>>(ACC, ML, out);
}

// Round 5
// 59.979 us; speedup vs baseline: 1.1385x; 1.1385x over previous
//
#include <hip/hip_runtime.h>

#define S_LEN 8192
#define DIM   256
#define CHUNK 512
#define TB    64
#define NIT   8
#define NBLK  256

typedef __attribute__((ext_vector_type(8))) short          short8;
typedef __attribute__((ext_vector_type(4))) unsigned short u16x4;
typedef __attribute__((ext_vector_type(4))) unsigned int   u32x4;
typedef __attribute__((ext_vector_type(4))) float          f32x4;
typedef __attribute__((ext_vector_type(8))) __bf16         bf16x8;

static __device__ __forceinline__ unsigned short f2bf(float f){
  unsigned int u = __builtin_bit_cast(unsigned int, f);
  u = (u + 0x7fffu + ((u >> 16) & 1u)) >> 16;   // RNE
  return (unsigned short)u;
}
static __device__ __forceinline__ float bf2f(unsigned short h){
  unsigned int u = ((unsigned int)h) << 16;
  return __builtin_bit_cast(float, u);
}
static __device__ __forceinline__ float fast_tanh(float x){
  float e = __expf(2.0f * x);
  return 1.0f - 2.0f / (e + 1.0f);
}
static __device__ __forceinline__ f32x4 mfma_bf16(short8 a, short8 b, f32x4 c){
  return __builtin_amdgcn_mfma_f32_16x16x32_bf16(
      __builtin_bit_cast(bf16x8, a), __builtin_bit_cast(bf16x8, b), c, 0, 0, 0);
}

// ---- prep: KT[n][k] = bf16(k_kernel[k][n])
__global__ void k_prep(const float* __restrict__ kk, unsigned short* __restrict__ KT){
  int idx = blockIdx.x * 512 + threadIdx.x;     // 128 x 512 = 65536
  int n = idx >> 8, k = idx & 255;
  KT[(n << 8) + k] = f2bf(kk[(k << 8) + n]);
}

// sXB  : element (r,d) at dblk*2048 + srow*32 + off ; dblk=d>>4, srow=r^(dblk&3),
//        off = ((d&15)*2) ^ (((srow>>2)&1)<<4)      (d-contiguous, for GEMM1-B)
// sXT2 : element (r,d) at d*128 + ((r*2) ^ (key(d)<<4)), key(d)=((d&3)<<1)^((d>>2)&7)
//        (r-contiguous, for GEMM3-B)

__global__ __launch_bounds__(512, 2) void k_main(
    const float* __restrict__ x, const int* __restrict__ mask,
    const float* __restrict__ ok, const unsigned short* __restrict__ KT,
    float* __restrict__ ACC, float* __restrict__ ML)
{
  __shared__ __align__(16) unsigned char sXB [32768];
  __shared__ __align__(16) unsigned char sXT2[32768];
  __shared__ __align__(16) unsigned char sT2 [32768];  // tanh(h) [64][256] bf16, swz ((row&7)<<4)
  __shared__ __align__(16) unsigned char sOT [16*528]; // O^T [16][256] bf16 (+pad), rows 8..15 zero
  __shared__ __align__(16) unsigned char sPT [16*144]; // P^T [16][64] bf16 (+pad)
  __shared__ float sWMax[4][16];
  __shared__ float sWSum[4][16];
  __shared__ float sMrun[16];
  __shared__ float sLrun[16];
  __shared__ float sFsc[16];
  __shared__ float sMaskB[CHUNK];

  const int tid = threadIdx.x;
  const int w   = tid >> 6;      // wave 0..7
  const int l   = tid & 63;
  const int l15 = l & 15;
  const int lhi = l >> 4;        // 0..3
  const int bid = blockIdx.x;
  const int b   = bid >> 4;
  const int chunk0 = (bid & 15) * CHUNK;

  // O^T init (heads 8..15 zero-padded)
  for (int idx = tid; idx < 16 * 256; idx += 512){
    int h = idx >> 8, k = idx & 255;
    float v = (h < 8) ? ok[k * 8 + h] : 0.0f;
    *(unsigned short*)(sOT + h * 528 + k * 2) = f2bf(v);
  }
  if (tid < 16){ sMrun[tid] = -1e30f; sLrun[tid] = 0.0f; }
  sMaskB[tid] = mask[(size_t)b * S_LEN + chunk0 + tid] ? 0.0f : 1e12f;

  // persistent K^T fragments: wave w owns hidden cols [32w, 32w+32)  (R1-proven)
  short8 aF[2][8];
  #pragma unroll
  for (int mi = 0; mi < 2; ++mi){
    int hidA = l15 + ((2*w + mi) << 4);
    #pragma unroll
    for (int k = 0; k < 8; ++k){
      int col = (k << 5) + (lhi << 3);
      aF[mi][k] = *(const short8*)((const unsigned char*)KT + (((size_t)hidA << 8) + col) * 2);
    }
  }

  const unsigned char* xb = (const unsigned char*)(x + ((size_t)b * S_LEN + chunk0) * DIM);

  // first tile into regs: wave w owns rows 8w..8w+7; lane l owns d = 4l..4l+3
  f32x4 xr[8];
  #pragma unroll
  for (int q = 0; q < 8; ++q)
    xr[q] = *(const f32x4*)(xb + (((size_t)(8*w + q)) * DIM + 4*l) * 4);

  f32x4 acc3[2];
  acc3[0] = (f32x4){0.f,0.f,0.f,0.f};
  acc3[1] = acc3[0];

  __syncthreads();

  for (int it = 0; it < NIT; ++it){
    // ---- P0: stage tile to sXB (natural) + sXT2 (transposed), prefetch next
    unsigned vd[8][2];
    #pragma unroll
    for (int q = 0; q < 8; ++q){
      vd[q][0] = (unsigned)f2bf(xr[q][0]) | ((unsigned)f2bf(xr[q][1]) << 16);
      vd[q][1] = (unsigned)f2bf(xr[q][2]) | ((unsigned)f2bf(xr[q][3]) << 16);
    }
    {
      int dblk = l >> 2;
      #pragma unroll
      for (int q = 0; q < 8; ++q){
        int r = 8*w + q;
        int srow = r ^ (dblk & 3);
        int off = ((l & 3) * 8) ^ (((srow >> 2) & 1) << 4);
        *(uint2*)(sXB + dblk * 2048 + srow * 32 + off) = make_uint2(vd[q][0], vd[q][1]);
      }
      #pragma unroll
      for (int i = 0; i < 4; ++i){
        int h = i >> 1;
        unsigned dwv[4];
        #pragma unroll
        for (int j = 0; j < 4; ++j){
          unsigned a = vd[2*j][h], c = vd[2*j+1][h];
          dwv[j] = (i & 1) ? ((a >> 16) | (c & 0xFFFF0000u))
                           : ((a & 0xFFFFu) | (c << 16));
        }
        int d = 4*l + i;
        int key = ((d & 3) << 1) ^ ((d >> 2) & 7);
        *(u32x4*)(sXT2 + d * 128 + ((16*w) ^ (key << 4))) =
            (u32x4){dwv[0], dwv[1], dwv[2], dwv[3]};
      }
    }
    if (it + 1 < NIT){
      #pragma unroll
      for (int q = 0; q < 8; ++q)
        xr[q] = *(const f32x4*)(xb + (((size_t)((it+1)*TB + 8*w + q)) * DIM + 4*l) * 4);
    }
    __syncthreads();

    // ---- P1: GEMM1^T: h^T[hid][row] = K^T · X^T ; tanh -> sT2[row][hid]
    #pragma unroll
    for (int nt = 0; nt < 4; ++nt){
      int row = l15 + (nt << 4);
      f32x4 a0 = (f32x4){0.f,0.f,0.f,0.f};
      f32x4 a1 = a0;
      #pragma unroll
      for (int k8 = 0; k8 < 8; ++k8){
        int dblkR = k8 * 2 + (lhi >> 1);
        int srowB = row ^ (dblkR & 3);
        int off = ((lhi & 1) * 16) ^ (((srowB >> 2) & 1) << 4);
        short8 bF = *(const short8*)(sXB + dblkR * 2048 + srowB * 32 + off);
        a0 = mfma_bf16(aF[0][k8], bF, a0);
        a1 = mfma_bf16(aF[1][k8], bF, a1);
      }
      #pragma unroll
      for (int mi = 0; mi < 2; ++mi){
        f32x4 av = mi ? a1 : a0;
        u16x4 tv;
        #pragma unroll
        for (int r = 0; r < 4; ++r) tv[r] = f2bf(fast_tanh(av[r]));
        int hidb2 = ((((2*w + mi) << 4) + (lhi << 2))) * 2;
        *(u16x4*)(sT2 + row * 512 + (hidb2 ^ ((row & 7) << 4))) = tv;
      }
    }
    __syncthreads();

    // ---- P2: GEMM2: scores[row][head] = tanh(h) · O   (waves 0..3)
    float sc[4];
    if (w < 4){
      int row = l15 + (w << 4);
      f32x4 a2 = (f32x4){0.f,0.f,0.f,0.f};
      #pragma unroll
      for (int k = 0; k < 8; ++k){
        int col2 = (k << 6) + (lhi << 4);
        short8 aT = *(const short8*)(sT2 + row * 512 + (col2 ^ ((row & 7) << 4)));
        short8 bO = *(const short8*)(sOT + l15 * 528 + col2);
        a2 = mfma_bf16(aT, bO, a2);
      }
      int rbase = (w << 4) + (lhi << 2);
      #pragma unroll
      for (int r = 0; r < 4; ++r)
        sc[r] = a2[r] - sMaskB[it * TB + rbase + r];
      float vm = fmaxf(fmaxf(sc[0], sc[1]), fmaxf(sc[2], sc[3]));
      vm = fmaxf(vm, __shfl_xor(vm, 16));
      vm = fmaxf(vm, __shfl_xor(vm, 32));
      if (l < 16) sWMax[w][l] = vm;
    }
    __syncthreads();

    // ---- P3: online-softmax bookkeeping + P tile (head index = l15 here)
    float m_old = sMrun[l15];
    float wm = fmaxf(fmaxf(sWMax[0][l15], sWMax[1][l15]),
                     fmaxf(sWMax[2][l15], sWMax[3][l15]));
    float m_new = fmaxf(m_old, wm);
    float fsc = __expf(m_old - m_new);
    if (w == 0 && l < 16) sFsc[l] = fsc;
    if (w < 4){
      float psum = 0.0f;
      int rbase = (w << 4) + (lhi << 2);
      #pragma unroll
      for (int r = 0; r < 4; ++r){
        float p = __expf(sc[r] - m_new);
        unsigned short pb = f2bf(p);
        psum += bf2f(pb);
        *(unsigned short*)(sPT + l15 * 144 + (rbase + r) * 2) = pb;
      }
      psum += __shfl_xor(psum, 16);
      psum += __shfl_xor(psum, 32);
      if (l < 16) sWSum[w][l] = psum;
    }
    __syncthreads();

    // ---- P4: GEMM3: pooled[head][d] += P^T · X
    // acc3[mi][r] holds head = lhi*4+r -> rescale with that head's factor
    #pragma unroll
    for (int r = 0; r < 4; ++r){
      float fr = sFsc[(lhi << 2) + r];
      acc3[0][r] *= fr;
      acc3[1][r] *= fr;
    }
    short8 aP0 = *(const short8*)(sPT + l15 * 144 + lhi * 16);        // r 0..31
    short8 aP1 = *(const short8*)(sPT + l15 * 144 + 64 + lhi * 16);   // r 32..63
    #pragma unroll
    for (int mi = 0; mi < 2; ++mi){
      int d = (2*w + mi) * 16 + l15;
      int key = ((d & 3) << 1) ^ ((d >> 2) & 7);
      const unsigned char* pd = sXT2 + d * 128;
      short8 b0 = *(const short8*)(pd + (((lhi * 16)      ) ^ (key << 4)));
      short8 b1 = *(const short8*)(pd + ((64 + lhi * 16) ^ (key << 4)));
      acc3[mi] = mfma_bf16(aP0, b0, acc3[mi]);
      acc3[mi] = mfma_bf16(aP1, b1, acc3[mi]);
    }
    if (w == 0 && l < 16){
      sLrun[l] = sLrun[l] * fsc + sWSum[0][l] + sWSum[1][l] + sWSum[2][l] + sWSum[3][l];
      sMrun[l] = m_new;
    }
    __syncthreads();
  }

  // epilogue: per-chunk partials.  acc3[mi]: head = lhi*4+reg, d = (2w+mi)*16 + l15
  if (lhi < 2){      // only heads 0..7 are real
    #pragma unroll
    for (int mi = 0; mi < 2; ++mi){
      int d = ((2*w + mi) << 4) + l15;
      #pragma unroll
      for (int r = 0; r < 4; ++r){
        int h = (lhi << 2) + r;
        ACC[((size_t)bid * 8 + h) * 256 + d] = acc3[mi][r];
      }
    }
  }
  if (w == 0 && l < 8){
    ML[bid * 16 + l]     = sMrun[l];
    ML[bid * 16 + 8 + l] = sLrun[l];
  }
}

// ---- merge 16 chunk-partials per (batch, head)
__global__ void k_merge(const float* __restrict__ ACC, const float* __restrict__ ML,
                        float* __restrict__ out){
  int b = blockIdx.x >> 3;
  int h = blockIdx.x & 7;
  int d = threadIdx.x;                      // 256
  float M = -1e30f;
  #pragma unroll
  for (int c = 0; c < 16; ++c) M = fmaxf(M, ML[(b * 16 + c) * 16 + h]);
  float L = 0.0f, V = 0.0f;
  #pragma unroll 4
  for (int c = 0; c < 16; ++c){
    int blk = b * 16 + c;
    float e = __expf(ML[blk * 16 + h] - M);
    L += e * ML[blk * 16 + 8 + h];
    V += e * ACC[((size_t)blk * 8 + h) * 256 + d];
  }
  out[(size_t)b * 2048 + h * 256 + d] = V / L;
}

extern "C" void kernel_launch(void* const* d_in, const int* in_sizes, int n_in,
                              void* d_out, int out_size, void* d_ws, size_t ws_size,
                              hipStream_t stream){
  const float* x   = (const float*)d_in[0];
  const int*  mask = (const int*) d_in[1];
  const float* kk  = (const float*)d_in[2];
  const float* ok  = (const float*)d_in[3];
  float* out = (float*)d_out;

  // ws layout: KT bf16 (128 KiB) | ACC f32 256*8*256 (2 MiB) | ML f32 256*16 (16 KiB)
  unsigned short* KT = (unsigned short*)d_ws;
  float* ACC = (float*)((char*)d_ws + 131072);
  float* ML  = (float*)((char*)d_ws + 131072 + 2097152);

  k_prep <<<128, 512, 0, stream>>>(kk, KT);
  k_main <<<NBLK, 512, 0, stream>>>(x, mask, ok, KT, ACC, ML);
  k_merge<<<128, 256, 0, stream>>>(ACC, ML, out);
}

// Round 6
// 59.828 us; speedup vs baseline: 1.1414x; 1.0025x over previous
//
#include <hip/hip_runtime.h>

#define S_LEN 8192
#define DIM   256
#define CHUNK 512
#define TB    64
#define NIT   8
#define NBLK  256

typedef __attribute__((ext_vector_type(8))) short          short8;
typedef __attribute__((ext_vector_type(4))) unsigned short u16x4;
typedef __attribute__((ext_vector_type(4))) unsigned int   u32x4;
typedef __attribute__((ext_vector_type(4))) float          f32x4;
typedef __attribute__((ext_vector_type(8))) __bf16         bf16x8;

static __device__ __forceinline__ unsigned short f2bf(float f){
  unsigned int u = __builtin_bit_cast(unsigned int, f);
  u = (u + 0x7fffu + ((u >> 16) & 1u)) >> 16;   // RNE
  return (unsigned short)u;
}
static __device__ __forceinline__ float bf2f(unsigned short h){
  unsigned int u = ((unsigned int)h) << 16;
  return __builtin_bit_cast(float, u);
}
static __device__ __forceinline__ float fast_tanh(float x){
  float e = __expf(2.0f * x);
  return 1.0f - 2.0f / (e + 1.0f);
}
static __device__ __forceinline__ f32x4 mfma_bf16(short8 a, short8 b, f32x4 c){
  return __builtin_amdgcn_mfma_f32_16x16x32_bf16(
      __builtin_bit_cast(bf16x8, a), __builtin_bit_cast(bf16x8, b), c, 0, 0, 0);
}
// barrier that drains LDS ops (cross-wave visibility) but leaves global
// prefetch loads in flight (no vmcnt drain — the __syncthreads() stall)
static __device__ __forceinline__ void softbar(){
  asm volatile("s_waitcnt lgkmcnt(0)\n\ts_barrier" ::: "memory");
}

// ---- prep: KT[n][k] = bf16(k_kernel[k][n])
__global__ void k_prep(const float* __restrict__ kk, unsigned short* __restrict__ KT){
  int idx = blockIdx.x * 512 + threadIdx.x;     // 128 x 512 = 65536
  int n = idx >> 8, k = idx & 255;
  KT[(n << 8) + k] = f2bf(kk[(k << 8) + n]);
}

// sXB  : element (r,d) at dblk*2048 + srow*32 + off ; dblk=d>>4, srow=r^(dblk&3),
//        off = ((d&15)*2) ^ (((srow>>2)&1)<<4)      (d-contiguous, for GEMM1-B)
// sXT2 : element (r,d) at d*128 + ((r*2) ^ (key(d)<<4)), key(d)=((d&3)<<1)^((d>>2)&7)
//        (r-contiguous, for GEMM3-B)

__global__ __launch_bounds__(512, 2) void k_main(
    const float* __restrict__ x, const int* __restrict__ mask,
    const float* __restrict__ ok, const unsigned short* __restrict__ KT,
    float* __restrict__ ACC, float* __restrict__ ML)
{
  __shared__ __align__(16) unsigned char sXB [32768];
  __shared__ __align__(16) unsigned char sXT2[32768];
  __shared__ __align__(16) unsigned char sT2 [32768];  // tanh(h) [64][256] bf16, swz ((row&7)<<4)
  __shared__ __align__(16) unsigned char sOT [16*528]; // O^T [16][256] bf16 (+pad), rows 8..15 zero
  __shared__ __align__(16) unsigned char sPT [16*144]; // P^T [16][64] bf16 (+pad)
  __shared__ float sWMax[4][16];
  __shared__ float sWSum[4][16];
  __shared__ float sMrun[16];
  __shared__ float sLrun[16];
  __shared__ float sFsc[16];
  __shared__ float sMaskB[CHUNK];

  const int tid = threadIdx.x;
  const int w   = tid >> 6;      // wave 0..7
  const int l   = tid & 63;
  const int l15 = l & 15;
  const int lhi = l >> 4;        // 0..3
  const int bid = blockIdx.x;
  const int b   = bid >> 4;
  const int chunk0 = (bid & 15) * CHUNK;

  // O^T init (heads 8..15 zero-padded)
  for (int idx = tid; idx < 16 * 256; idx += 512){
    int h = idx >> 8, k = idx & 255;
    float v = (h < 8) ? ok[k * 8 + h] : 0.0f;
    *(unsigned short*)(sOT + h * 528 + k * 2) = f2bf(v);
  }
  if (tid < 16){ sMrun[tid] = -1e30f; sLrun[tid] = 0.0f; }
  sMaskB[tid] = mask[(size_t)b * S_LEN + chunk0 + tid] ? 0.0f : 1e12f;

  // persistent K^T fragments: wave w owns hidden cols [32w, 32w+32)
  short8 aF[2][8];
  #pragma unroll
  for (int mi = 0; mi < 2; ++mi){
    int hidA = l15 + ((2*w + mi) << 4);
    #pragma unroll
    for (int k = 0; k < 8; ++k){
      int col = (k << 5) + (lhi << 3);
      aF[mi][k] = *(const short8*)((const unsigned char*)KT + (((size_t)hidA << 8) + col) * 2);
    }
  }

  const unsigned char* xb = (const unsigned char*)(x + ((size_t)b * S_LEN + chunk0) * DIM);

  // first tile into regs: wave w owns rows 8w..8w+7; lane l owns d = 4l..4l+3
  f32x4 xr[8];
  #pragma unroll
  for (int q = 0; q < 8; ++q)
    xr[q] = *(const f32x4*)(xb + (((size_t)(8*w + q)) * DIM + 4*l) * 4);

  f32x4 acc3[2];
  acc3[0] = (f32x4){0.f,0.f,0.f,0.f};
  acc3[1] = acc3[0];

  __syncthreads();

  for (int it = 0; it < NIT; ++it){
    // ---- P0: stage tile to sXB (natural) + sXT2 (transposed), prefetch next
    unsigned vd[8][2];
    #pragma unroll
    for (int q = 0; q < 8; ++q){
      vd[q][0] = (unsigned)f2bf(xr[q][0]) | ((unsigned)f2bf(xr[q][1]) << 16);
      vd[q][1] = (unsigned)f2bf(xr[q][2]) | ((unsigned)f2bf(xr[q][3]) << 16);
    }
    {
      int dblk = l >> 2;
      #pragma unroll
      for (int q = 0; q < 8; ++q){
        int r = 8*w + q;
        int srow = r ^ (dblk & 3);
        int off = ((l & 3) * 8) ^ (((srow >> 2) & 1) << 4);
        *(uint2*)(sXB + dblk * 2048 + srow * 32 + off) = make_uint2(vd[q][0], vd[q][1]);
      }
      #pragma unroll
      for (int i = 0; i < 4; ++i){
        int h = i >> 1;
        unsigned dwv[4];
        #pragma unroll
        for (int j = 0; j < 4; ++j){
          unsigned a = vd[2*j][h], c = vd[2*j+1][h];
          dwv[j] = (i & 1) ? ((a >> 16) | (c & 0xFFFF0000u))
                           : ((a & 0xFFFFu) | (c << 16));
        }
        int d = 4*l + i;
        int key = ((d & 3) << 1) ^ ((d >> 2) & 7);
        *(u32x4*)(sXT2 + d * 128 + ((16*w) ^ (key << 4))) =
            (u32x4){dwv[0], dwv[1], dwv[2], dwv[3]};
      }
    }
    if (it + 1 < NIT){
      #pragma unroll
      for (int q = 0; q < 8; ++q)
        xr[q] = *(const f32x4*)(xb + (((size_t)((it+1)*TB + 8*w + q)) * DIM + 4*l) * 4);
    }
    softbar();

    // ---- P1: GEMM1^T: h^T[hid][row] = K^T · X^T ; tanh -> sT2[row][hid]
    #pragma unroll
    for (int nt = 0; nt < 4; ++nt){
      int row = l15 + (nt << 4);
      f32x4 a0 = (f32x4){0.f,0.f,0.f,0.f};
      f32x4 a1 = a0;
      #pragma unroll
      for (int k8 = 0; k8 < 8; ++k8){
        int dblkR = k8 * 2 + (lhi >> 1);
        int srowB = row ^ (dblkR & 3);
        int off = ((lhi & 1) * 16) ^ (((srowB >> 2) & 1) << 4);
        short8 bF = *(const short8*)(sXB + dblkR * 2048 + srowB * 32 + off);
        a0 = mfma_bf16(aF[0][k8], bF, a0);
        a1 = mfma_bf16(aF[1][k8], bF, a1);
      }
      #pragma unroll
      for (int mi = 0; mi < 2; ++mi){
        f32x4 av = mi ? a1 : a0;
        u16x4 tv;
        #pragma unroll
        for (int r = 0; r < 4; ++r) tv[r] = f2bf(fast_tanh(av[r]));
        int hidb2 = ((((2*w + mi) << 4) + (lhi << 2))) * 2;
        *(u16x4*)(sT2 + row * 512 + (hidb2 ^ ((row & 7) << 4))) = tv;
      }
    }
    softbar();

    // ---- P2: GEMM2: scores[row][head] = tanh(h) · O   (waves 0..3)
    float sc[4];
    if (w < 4){
      int row = l15 + (w << 4);
      f32x4 a2 = (f32x4){0.f,0.f,0.f,0.f};
      #pragma unroll
      for (int k = 0; k < 8; ++k){
        int col2 = (k << 6) + (lhi << 4);
        short8 aT = *(const short8*)(sT2 + row * 512 + (col2 ^ ((row & 7) << 4)));
        short8 bO = *(const short8*)(sOT + l15 * 528 + col2);
        a2 = mfma_bf16(aT, bO, a2);
      }
      int rbase = (w << 4) + (lhi << 2);
      #pragma unroll
      for (int r = 0; r < 4; ++r)
        sc[r] = a2[r] - sMaskB[it * TB + rbase + r];
      float vm = fmaxf(fmaxf(sc[0], sc[1]), fmaxf(sc[2], sc[3]));
      vm = fmaxf(vm, __shfl_xor(vm, 16));
      vm = fmaxf(vm, __shfl_xor(vm, 32));
      if (l < 16) sWMax[w][l] = vm;
    }
    softbar();

    // ---- P3: online-softmax bookkeeping + P tile (head index = l15 here)
    float m_old = sMrun[l15];
    float wm = fmaxf(fmaxf(sWMax[0][l15], sWMax[1][l15]),
                     fmaxf(sWMax[2][l15], sWMax[3][l15]));
    float m_new = fmaxf(m_old, wm);
    float fsc = __expf(m_old - m_new);
    if (w == 0 && l < 16) sFsc[l] = fsc;
    if (w < 4){
      float psum = 0.0f;
      int rbase = (w << 4) + (lhi << 2);
      #pragma unroll
      for (int r = 0; r < 4; ++r){
        float p = __expf(sc[r] - m_new);
        unsigned short pb = f2bf(p);
        psum += bf2f(pb);
        *(unsigned short*)(sPT + l15 * 144 + (rbase + r) * 2) = pb;
      }
      psum += __shfl_xor(psum, 16);
      psum += __shfl_xor(psum, 32);
      if (l < 16) sWSum[w][l] = psum;
    }
    softbar();

    // ---- P4: GEMM3: pooled[head][d] += P^T · X
    // acc3[mi][r] holds head = lhi*4+r -> rescale with that head's factor
    #pragma unroll
    for (int r = 0; r < 4; ++r){
      float fr = sFsc[(lhi << 2) + r];
      acc3[0][r] *= fr;
      acc3[1][r] *= fr;
    }
    short8 aP0 = *(const short8*)(sPT + l15 * 144 + lhi * 16);        // r 0..31
    short8 aP1 = *(const short8*)(sPT + l15 * 144 + 64 + lhi * 16);   // r 32..63
    #pragma unroll
    for (int mi = 0; mi < 2; ++mi){
      int d = (2*w + mi) * 16 + l15;
      int key = ((d & 3) << 1) ^ ((d >> 2) & 7);
      const unsigned char* pd = sXT2 + d * 128;
      short8 b0 = *(const short8*)(pd + (((lhi * 16)      ) ^ (key << 4)));
      short8 b1 = *(const short8*)(pd + ((64 + lhi * 16) ^ (key << 4)));
      acc3[mi] = mfma_bf16(aP0, b0, acc3[mi]);
      acc3[mi] = mfma_bf16(aP1, b1, acc3[mi]);
    }
    if (w == 0 && l < 16){
      sLrun[l] = sLrun[l] * fsc + sWSum[0][l] + sWSum[1][l] + sWSum[2][l] + sWSum[3][l];
      sMrun[l] = m_new;
    }
    softbar();
  }

  // epilogue: per-chunk partials.  acc3[mi]: head = lhi*4+reg, d = (2w+mi)*16 + l15
  if (lhi < 2){      // only heads 0..7 are real
    #pragma unroll
    for (int mi = 0; mi < 2; ++mi){
      int d = ((2*w + mi) << 4) + l15;
      #pragma unroll
      for (int r = 0; r < 4; ++r){
        int h = (lhi << 2) + r;
        ACC[((size_t)bid * 8 + h) * 256 + d] = acc3[mi][r];
      }
    }
  }
  if (w == 0 && l < 8){
    ML[bid * 16 + l]     = sMrun[l];
    ML[bid * 16 + 8 + l] = sLrun[l];
  }
}

// ---- merge 16 chunk-partials per (batch, head)
__global__ void k_merge(const float* __restrict__ ACC, const float* __restrict__ ML,
                        float* __restrict__ out){
  int b = blockIdx.x >> 3;
  int h = blockIdx.x & 7;
  int d = threadIdx.x;                      // 256
  float M = -1e30f;
  #pragma unroll
  for (int c = 0; c < 16; ++c) M = fmaxf(M, ML[(b * 16 + c) * 16 + h]);
  float L = 0.0f, V = 0.0f;
  #pragma unroll 4
  for (int c = 0; c < 16; ++c){
    int blk = b * 16 + c;
    float e = __expf(ML[blk * 16 + h] - M);
    L += e * ML[blk * 16 + 8 + h];
    V += e * ACC[((size_t)blk * 8 + h) * 256 + d];
  }
  out[(size_t)b * 2048 + h * 256 + d] = V / L;
}

extern "C" void kernel_launch(void* const* d_in, const int* in_sizes, int n_in,
                              void* d_out, int out_size, void* d_ws, size_t ws_size,
                              hipStream_t stream){
  const float* x   = (const float*)d_in[0];
  const int*  mask = (const int*) d_in[1];
  const float* kk  = (const float*)d_in[2];
  const float* ok  = (const float*)d_in[3];
  float* out = (float*)d_out;

  // ws layout: KT bf16 (128 KiB) | ACC f32 256*8*256 (2 MiB) | ML f32 256*16 (16 KiB)
  unsigned short* KT = (unsigned short*)d_ws;
  float* ACC = (float*)((char*)d_ws + 131072);
  float* ML  = (float*)((char*)d_ws + 131072 + 2097152);

  k_prep <<<128, 512, 0, stream>>>(kk, KT);
  k_main <<<NBLK, 512, 0, stream>>>(x, mask, ok, KT, ACC, ML);
  k_merge<<<128, 256, 0, stream>>>(ACC, ML, out);
}